// Round 1
// baseline (138.968 us; speedup 1.0000x reference)
//
#include <hip/hip_runtime.h>
#include <cstdint>

typedef float   f32x4  __attribute__((ext_vector_type(4)));
typedef __bf16  bf16x4 __attribute__((ext_vector_type(4)));
typedef __bf16  bf16x8 __attribute__((ext_vector_type(8)));

#if __has_builtin(__builtin_amdgcn_exp2f)
#define EXP2F(x) __builtin_amdgcn_exp2f(x)
#else
#define EXP2F(x) exp2f(x)
#endif

#define BT_TOTAL 512
#define NNODES 170
#define CDIM 128
#define HEADS 8
#define HDIM 16
#define SLAB (NNODES*HDIM)                 // 2720
#define QKV_ELEMS (BT_TOTAL*HEADS*SLAB)    // 11,141,120
#define OUT_ELEMS (BT_TOTAL*NNODES*CDIM)   // 11,141,120

// ---------------------------------------------------------------- weights -> bf16
__global__ void wconv_kernel(const float* __restrict__ wq, const float* __restrict__ wk,
                             const float* __restrict__ wv, const float* __restrict__ wo,
                             __bf16* __restrict__ wbf) {
    int i = blockIdx.x * 256 + threadIdx.x;
    if (i < 128 * 128) {
        wbf[i]         = (__bf16)wq[i];
        wbf[16384 + i] = (__bf16)wk[i];
        wbf[32768 + i] = (__bf16)wv[i];
        wbf[49152 + i] = (__bf16)wo[i];
    }
}

// ---------------------------------------------------------------- QKV projection
// out[bt][h][n][d] (bf16) = X[bt*170+n][:] @ W[h*16+d][:] + bias
__global__ __launch_bounds__(256) void proj_kernel(const float* __restrict__ X,
                                                   const __bf16* __restrict__ W,
                                                   const float* __restrict__ bias,
                                                   __bf16* __restrict__ out) {
    __shared__ __bf16 Wl[128 * 132];
    int t = threadIdx.x;
    int bt = blockIdx.x / 3, mt = blockIdx.x % 3;
    // stage weight matrix (bf16) into LDS, pad 132 for bank spread
    #pragma unroll
    for (int i = 0; i < 16; ++i) {
        int idx = i * 256 + t;              // 4096 chunks of 4 bf16
        int r = idx >> 5, c = (idx & 31) * 4;
        *(bf16x4*)&Wl[r * 132 + c] = *(const bf16x4*)&W[r * 128 + c];
    }
    __syncthreads();

    int w = t >> 6, lane = t & 63;
    int li = lane & 15, l4 = lane >> 4;
    int r0 = mt * 64;
    int mrow = r0 + w * 16 + li;            // node index this lane's A-rows
    bool mvalid = (mrow < NNODES);
    const float* xrow = X + ((size_t)(bt * NNODES + mrow)) * CDIM;
    f32x4 zf = {0.f, 0.f, 0.f, 0.f};
    f32x4 acc[8] = {};
    #pragma unroll
    for (int kk = 0; kk < 4; ++kk) {
        int kb = kk * 32 + l4 * 4;
        f32x4 a0 = mvalid ? *(const f32x4*)(xrow + kb)      : zf;
        f32x4 a1 = mvalid ? *(const f32x4*)(xrow + kb + 16) : zf;
        bf16x8 a = { (__bf16)a0[0], (__bf16)a0[1], (__bf16)a0[2], (__bf16)a0[3],
                     (__bf16)a1[0], (__bf16)a1[1], (__bf16)a1[2], (__bf16)a1[3] };
        #pragma unroll
        for (int nt = 0; nt < 8; ++nt) {
            int c = nt * 16 + li;
            bf16x4 b0 = *(const bf16x4*)&Wl[c * 132 + kb];
            bf16x4 b1 = *(const bf16x4*)&Wl[c * 132 + kb + 16];
            bf16x8 b = __builtin_shufflevector(b0, b1, 0, 1, 2, 3, 4, 5, 6, 7);
            acc[nt] = __builtin_amdgcn_mfma_f32_16x16x32_bf16(a, b, acc[nt], 0, 0, 0);
        }
    }
    // epilogue: C layout col=li (=channel), row=4*l4+reg (=node offset)
    #pragma unroll
    for (int nt = 0; nt < 8; ++nt) {
        int c = nt * 16 + li;
        float bvv = bias[c];
        int h = nt, d = li;
        #pragma unroll
        for (int r = 0; r < 4; ++r) {
            int n = r0 + w * 16 + l4 * 4 + r;
            if (n < NNODES)
                out[((size_t)(bt * HEADS + h)) * SLAB + n * HDIM + d] = (__bf16)(acc[nt][r] + bvv);
        }
    }
}

// ---------------------------------------------------------------- attention core
// block = bt, wave = head. S^T = mfma(K, Q): C col(lane&15)=q, row=key -> softmax
// over key (per-lane 44 vals + shfl_xor 16/32), P tiles feed PV mfma B-operand
// directly; A-operand = V^T packed with the SAME k-mapping (layout-invariant).
__global__ __launch_bounds__(512) void attn_kernel(const __bf16* __restrict__ qws,
                                                   const __bf16* __restrict__ kws,
                                                   const __bf16* __restrict__ vws,
                                                   __bf16* __restrict__ ows) {
    int bt = blockIdx.x;
    int w = threadIdx.x >> 6, lane = threadIdx.x & 63;
    int li = lane & 15, l4 = lane >> 4;
    const __bf16* qb = qws + ((size_t)(bt * HEADS + w)) * SLAB;
    const __bf16* kb = kws + ((size_t)(bt * HEADS + w)) * SLAB;
    const __bf16* vb = vws + ((size_t)(bt * HEADS + w)) * SLAB;
    __bf16* ob = ows + (size_t)bt * NNODES * CDIM;
    const __bf16 bz = (__bf16)0.0f;
    const bf16x4 z4 = {bz, bz, bz, bz};
    f32x4 zf = {0.f, 0.f, 0.f, 0.f};

    // K fragments: tile tt covers keys 16tt..16tt+15; A row m=key(li), k=d=4*l4+j
    bf16x4 kf[11];
    #pragma unroll
    for (int tt = 0; tt < 11; ++tt)
        kf[tt] = *(const bf16x4*)&kb[(tt * 16 + li) * HDIM + l4 * 4];

    // V^T fragments: m=d(li), k=key = 32s + 4*l4 + (j&3) + 16*(j>>2); zero keys>=170
    bf16x8 vf[6];
    #pragma unroll
    for (int s = 0; s < 6; ++s) {
        #pragma unroll
        for (int j = 0; j < 8; ++j) {
            int key = 32 * s + 4 * l4 + (j & 3) + 16 * (j >> 2);
            vf[s][j] = (key < NNODES) ? vb[key * HDIM + li] : bz;
        }
    }

    const float s2 = 0.12753851f;  // log2(e) / sqrt(128)
    #pragma unroll 1
    for (int qc = 0; qc < 11; ++qc) {
        bf16x4 qv = *(const bf16x4*)&qb[(qc * 16 + li) * HDIM + l4 * 4];
        bf16x8 qf = __builtin_shufflevector(qv, z4, 0, 1, 2, 3, 4, 5, 6, 7);
        f32x4 e[11];
        #pragma unroll
        for (int tt = 0; tt < 11; ++tt) {
            bf16x8 a = __builtin_shufflevector(kf[tt], z4, 0, 1, 2, 3, 4, 5, 6, 7);
            e[tt] = __builtin_amdgcn_mfma_f32_16x16x32_bf16(a, qf, zf, 0, 0, 0);
        }
        // scale + mask padded keys + row max (per column q = li)
        float mx = -3.0e38f;
        #pragma unroll
        for (int tt = 0; tt < 11; ++tt) {
            #pragma unroll
            for (int r = 0; r < 4; ++r) {
                float v = e[tt][r] * s2;
                if (tt == 10 && (160 + l4 * 4 + r) >= NNODES) v = -1.0e30f;
                e[tt][r] = v;
                mx = fmaxf(mx, v);
            }
        }
        mx = fmaxf(mx, __shfl_xor(mx, 16));
        mx = fmaxf(mx, __shfl_xor(mx, 32));
        float sum = 0.f;
        #pragma unroll
        for (int tt = 0; tt < 11; ++tt) {
            #pragma unroll
            for (int r = 0; r < 4; ++r) {
                float p = EXP2F(e[tt][r] - mx);
                e[tt][r] = p;
                sum += p;
            }
        }
        sum += __shfl_xor(sum, 16);
        sum += __shfl_xor(sum, 32);
        float inv = 1.0f / sum;
        // P -> bf16 B-fragments: elems 0-3 = tile 2s regs, elems 4-7 = tile 2s+1
        bf16x8 pv[6];
        #pragma unroll
        for (int s = 0; s < 5; ++s) {
            bf16x8 tmp = { (__bf16)e[2*s][0],   (__bf16)e[2*s][1],   (__bf16)e[2*s][2],   (__bf16)e[2*s][3],
                           (__bf16)e[2*s+1][0], (__bf16)e[2*s+1][1], (__bf16)e[2*s+1][2], (__bf16)e[2*s+1][3] };
            pv[s] = tmp;
        }
        {
            bf16x8 tmp = { (__bf16)e[10][0], (__bf16)e[10][1], (__bf16)e[10][2], (__bf16)e[10][3],
                           bz, bz, bz, bz };
            pv[5] = tmp;
        }
        f32x4 o = zf;
        #pragma unroll
        for (int s = 0; s < 6; ++s)
            o = __builtin_amdgcn_mfma_f32_16x16x32_bf16(vf[s], pv[s], o, 0, 0, 0);
        // O^T C-tile: col=li=q, row=4*l4+r=d
        int q = qc * 16 + li;
        if (q < NNODES) {
            #pragma unroll
            for (int r = 0; r < 4; ++r) {
                int d = l4 * 4 + r;
                ob[q * CDIM + w * HDIM + d] = (__bf16)(o[r] * inv);
            }
        }
    }
}

// ---------------------------------------------------------------- output projection
__global__ __launch_bounds__(256) void oproj_kernel(const __bf16* __restrict__ ows,
                                                    const __bf16* __restrict__ W,
                                                    const float* __restrict__ bias,
                                                    float* __restrict__ out) {
    __shared__ __bf16 Wl[128 * 132];
    int t = threadIdx.x;
    int bt = blockIdx.x / 3, mt = blockIdx.x % 3;
    #pragma unroll
    for (int i = 0; i < 16; ++i) {
        int idx = i * 256 + t;
        int r = idx >> 5, c = (idx & 31) * 4;
        *(bf16x4*)&Wl[r * 132 + c] = *(const bf16x4*)&W[r * 128 + c];
    }
    __syncthreads();

    int w = t >> 6, lane = t & 63;
    int li = lane & 15, l4 = lane >> 4;
    int r0 = mt * 64;
    int mrow = r0 + w * 16 + li;
    bool mvalid = (mrow < NNODES);
    const __bf16* arow = ows + ((size_t)bt * NNODES + mrow) * CDIM;
    const __bf16 bz = (__bf16)0.0f;
    const bf16x4 z4 = {bz, bz, bz, bz};
    f32x4 acc[8] = {};
    #pragma unroll
    for (int kk = 0; kk < 4; ++kk) {
        int kb = kk * 32 + l4 * 4;
        bf16x4 a0 = mvalid ? *(const bf16x4*)(arow + kb)      : z4;
        bf16x4 a1 = mvalid ? *(const bf16x4*)(arow + kb + 16) : z4;
        bf16x8 a = __builtin_shufflevector(a0, a1, 0, 1, 2, 3, 4, 5, 6, 7);
        #pragma unroll
        for (int nt = 0; nt < 8; ++nt) {
            int c = nt * 16 + li;
            bf16x4 b0 = *(const bf16x4*)&Wl[c * 132 + kb];
            bf16x4 b1 = *(const bf16x4*)&Wl[c * 132 + kb + 16];
            bf16x8 b = __builtin_shufflevector(b0, b1, 0, 1, 2, 3, 4, 5, 6, 7);
            acc[nt] = __builtin_amdgcn_mfma_f32_16x16x32_bf16(a, b, acc[nt], 0, 0, 0);
        }
    }
    #pragma unroll
    for (int nt = 0; nt < 8; ++nt) {
        int c = nt * 16 + li;
        float bvv = bias[c];
        #pragma unroll
        for (int r = 0; r < 4; ++r) {
            int n = r0 + w * 16 + l4 * 4 + r;
            if (n < NNODES)
                out[((size_t)bt * NNODES + n) * CDIM + c] = acc[nt][r] + bvv;
        }
    }
}

// ---------------------------------------------------------------- launch
extern "C" void kernel_launch(void* const* d_in, const int* in_sizes, int n_in,
                              void* d_out, int out_size, void* d_ws, size_t ws_size,
                              hipStream_t stream) {
    const float* values = (const float*)d_in[0];
    const float* keys   = (const float*)d_in[1];
    const float* query  = (const float*)d_in[2];
    const float* bv = (const float*)d_in[4];
    const float* bk = (const float*)d_in[6];
    const float* bq = (const float*)d_in[8];
    const float* bo = (const float*)d_in[10];
    const float* Wv = (const float*)d_in[3];
    const float* Wk = (const float*)d_in[5];
    const float* Wq = (const float*)d_in[7];
    const float* Wo = (const float*)d_in[9];
    float* out = (float*)d_out;

    __bf16* qws = (__bf16*)d_ws;
    __bf16* kws = qws + QKV_ELEMS;
    __bf16* vws = kws + QKV_ELEMS;
    __bf16* ows = vws + QKV_ELEMS;
    __bf16* wbf = ows + OUT_ELEMS;   // [Wq|Wk|Wv|Wo] bf16, 16384 each

    hipLaunchKernelGGL(wconv_kernel, dim3(64),   dim3(256), 0, stream, Wq, Wk, Wv, Wo, wbf);
    hipLaunchKernelGGL(proj_kernel,  dim3(1536), dim3(256), 0, stream, query,  wbf,          bq, qws);
    hipLaunchKernelGGL(proj_kernel,  dim3(1536), dim3(256), 0, stream, keys,   wbf + 16384,  bk, kws);
    hipLaunchKernelGGL(proj_kernel,  dim3(1536), dim3(256), 0, stream, values, wbf + 32768,  bv, vws);
    hipLaunchKernelGGL(attn_kernel,  dim3(512),  dim3(512), 0, stream, qws, kws, vws, ows);
    hipLaunchKernelGGL(oproj_kernel, dim3(1536), dim3(256), 0, stream, ows, wbf + 49152,  bo, out);
}

// Round 2
// 118.048 us; speedup vs baseline: 1.1772x; 1.1772x over previous
//
#include <hip/hip_runtime.h>
#include <cstdint>

typedef float   f32x4  __attribute__((ext_vector_type(4)));
typedef __bf16  bf16x4 __attribute__((ext_vector_type(4)));
typedef __bf16  bf16x8 __attribute__((ext_vector_type(8)));

#if __has_builtin(__builtin_amdgcn_exp2f)
#define EXP2F(x) __builtin_amdgcn_exp2f(x)
#else
#define EXP2F(x) exp2f(x)
#endif

#define BT_TOTAL 512
#define NNODES 170
#define CDIM 128
#define HEADS 8
#define HDIM 16
#define SLAB (NNODES*HDIM)           // 2720
#define NPAD 172                     // V^T row stride (4-aligned)
#define VSLAB (HDIM*NPAD)            // 2752
#define QKV_ELEMS ((size_t)BT_TOTAL*HEADS*SLAB)   // 11,141,120
#define S2L2E 0.12753851f            // log2(e)/sqrt(128), folded into Wq/bq

// ---------------------------------------------------------------- fused QKV projection
// iid 0=q -> qws [bt][h][n][d] (W,b pre-scaled by S2L2E)
// iid 1=k -> kws [bt][h][n][d]
// iid 2=v -> vt  [bt][h][d][NPAD]  (transposed, lives in d_out scratch)
__global__ __launch_bounds__(512) void qkv_kernel(const float* __restrict__ qin,
    const float* __restrict__ kin, const float* __restrict__ vin,
    const float* __restrict__ Wq, const float* __restrict__ Wk, const float* __restrict__ Wv,
    const float* __restrict__ bq, const float* __restrict__ bk, const float* __restrict__ bv,
    __bf16* __restrict__ qws, __bf16* __restrict__ kws, __bf16* __restrict__ vt) {
    __shared__ __bf16 Wl[128 * 132];
    int t = threadIdx.x;
    int iid = blockIdx.x / BT_TOTAL;
    int bt  = blockIdx.x % BT_TOTAL;
    const float* X    = (iid == 0) ? qin : (iid == 1) ? kin : vin;
    const float* W    = (iid == 0) ? Wq  : (iid == 1) ? Wk  : Wv;
    const float* bias = (iid == 0) ? bq  : (iid == 1) ? bk  : bv;
    float wscale = (iid == 0) ? S2L2E : 1.0f;
    // stage W (f32 -> bf16, scaled) into LDS: 4096 f32x4 chunks / 512 threads
    #pragma unroll
    for (int i = 0; i < 8; ++i) {
        int idx = i * 512 + t;
        int r = idx >> 5, c = (idx & 31) * 4;
        f32x4 w4 = *(const f32x4*)&W[r * 128 + c];
        bf16x4 wb = { (__bf16)(w4[0] * wscale), (__bf16)(w4[1] * wscale),
                      (__bf16)(w4[2] * wscale), (__bf16)(w4[3] * wscale) };
        *(bf16x4*)&Wl[r * 132 + c] = wb;
    }
    __syncthreads();

    int w = t >> 6, lane = t & 63, li = lane & 15, l4 = lane >> 4;
    const bf16x4 z4 = {(__bf16)0.f, (__bf16)0.f, (__bf16)0.f, (__bf16)0.f};
    f32x4 zf = {0.f, 0.f, 0.f, 0.f};
    for (int mt = 0; mt < 2; ++mt) {
        int tbase = mt * 128 + w * 16;           // this wave's 16-row tile base
        if (tbase >= NNODES) break;              // wave-uniform skip
        int mrow = tbase + li;
        bool mvalid = mrow < NNODES;
        const float* xrow = X + ((size_t)(bt * NNODES + mrow)) * CDIM;
        f32x4 acc[8] = {};
        #pragma unroll
        for (int kk = 0; kk < 4; ++kk) {
            int kb = kk * 32 + l4 * 4;
            f32x4 a0 = mvalid ? *(const f32x4*)(xrow + kb)      : zf;
            f32x4 a1 = mvalid ? *(const f32x4*)(xrow + kb + 16) : zf;
            bf16x8 a = { (__bf16)a0[0], (__bf16)a0[1], (__bf16)a0[2], (__bf16)a0[3],
                         (__bf16)a1[0], (__bf16)a1[1], (__bf16)a1[2], (__bf16)a1[3] };
            #pragma unroll
            for (int nt = 0; nt < 8; ++nt) {
                int c = nt * 16 + li;
                bf16x4 b0 = *(const bf16x4*)&Wl[c * 132 + kb];
                bf16x4 b1 = *(const bf16x4*)&Wl[c * 132 + kb + 16];
                bf16x8 b = __builtin_shufflevector(b0, b1, 0, 1, 2, 3, 4, 5, 6, 7);
                acc[nt] = __builtin_amdgcn_mfma_f32_16x16x32_bf16(a, b, acc[nt], 0, 0, 0);
            }
        }
        if (iid < 2) {
            __bf16* out = ((iid == 0) ? qws : kws) + ((size_t)bt * HEADS) * SLAB;
            #pragma unroll
            for (int nt = 0; nt < 8; ++nt) {
                int c = nt * 16 + li;              // h = nt, d = li
                float bval = bias[c] * wscale;
                #pragma unroll
                for (int r = 0; r < 4; ++r) {
                    int n = tbase + l4 * 4 + r;
                    if (n < NNODES)
                        out[(size_t)nt * SLAB + n * HDIM + li] = (__bf16)(acc[nt][r] + bval);
                }
            }
        } else {
            __bf16* out = vt + ((size_t)bt * HEADS) * VSLAB;
            int n0 = tbase + l4 * 4;
            #pragma unroll
            for (int nt = 0; nt < 8; ++nt) {
                int c = nt * 16 + li;              // h = nt, d = li
                float bval = bias[c];
                __bf16* dst = out + (size_t)nt * VSLAB + li * NPAD + n0;
                if (n0 + 3 < NNODES) {
                    bf16x4 o4 = { (__bf16)(acc[nt][0] + bval), (__bf16)(acc[nt][1] + bval),
                                  (__bf16)(acc[nt][2] + bval), (__bf16)(acc[nt][3] + bval) };
                    *(bf16x4*)dst = o4;
                } else {
                    #pragma unroll
                    for (int r = 0; r < 4; ++r)
                        if (n0 + r < NNODES) dst[r] = (__bf16)(acc[nt][r] + bval);
                }
            }
        }
    }
}

// ---------------------------------------------------------------- attention core
// one wave per (bt, h, q-half); S^T = mfma(K, Q): col=li=q, row=key.
// No max-subtraction (energies pre-scaled, bounded); masked keys are SELECTED
// to zero (never multiplied) so stale bytes can't produce NaN.
__global__ __launch_bounds__(64, 4) void attn_kernel(const __bf16* __restrict__ qws,
                                                     const __bf16* __restrict__ kws,
                                                     const __bf16* __restrict__ vt,
                                                     __bf16* __restrict__ ows) {
    int bid = blockIdx.x;
    int half = bid & 1, bh = bid >> 1;
    int bt = bh >> 3, h = bh & 7;
    int lane = threadIdx.x & 63, li = lane & 15, l4 = lane >> 4;
    const __bf16* qb  = qws + ((size_t)(bt * HEADS + h)) * SLAB;
    const __bf16* kb  = kws + ((size_t)(bt * HEADS + h)) * SLAB;
    const __bf16* vtb = vt  + ((size_t)(bt * HEADS + h)) * VSLAB;
    __bf16* ob = ows + (size_t)bt * NNODES * CDIM + h * HDIM;
    const __bf16 bz = (__bf16)0.0f;
    const bf16x4 z4 = {bz, bz, bz, bz};
    const f32x4 zf = {0.f, 0.f, 0.f, 0.f};

    // K fragments: tile tt = keys 16tt..16tt+15; A row m=key(li), k=d=4*l4+j
    bf16x4 kf[11];
    #pragma unroll
    for (int tt = 0; tt < 11; ++tt)
        kf[tt] = *(const bf16x4*)&kb[(tt * 16 + li) * HDIM + l4 * 4];

    // V^T fragments from vt rows: vf[s][j] = V[32s+4*l4+(j&3)+16*(j>>2)][li]
    bf16x8 vf[6];
    #pragma unroll
    for (int s = 0; s < 5; ++s) {
        bf16x4 a = *(const bf16x4*)&vtb[li * NPAD + 32 * s + 4 * l4];
        bf16x4 b = *(const bf16x4*)&vtb[li * NPAD + 32 * s + 4 * l4 + 16];
        vf[s] = __builtin_shufflevector(a, b, 0, 1, 2, 3, 4, 5, 6, 7);
    }
    {
        bf16x4 a = *(const bf16x4*)&vtb[li * NPAD + 160 + 4 * l4];
        bf16x8 v5 = { (160 + 4 * l4 + 0 < NNODES) ? a[0] : bz,
                      (160 + 4 * l4 + 1 < NNODES) ? a[1] : bz,
                      (160 + 4 * l4 + 2 < NNODES) ? a[2] : bz,
                      (160 + 4 * l4 + 3 < NNODES) ? a[3] : bz,
                      bz, bz, bz, bz };
        vf[5] = v5;
    }
    // P-mask for key tile 10 (keys 160..175)
    f32x4 mk = { (160 + l4 * 4 + 0 < NNODES) ? 1.f : 0.f,
                 (160 + l4 * 4 + 1 < NNODES) ? 1.f : 0.f,
                 (160 + l4 * 4 + 2 < NNODES) ? 1.f : 0.f,
                 (160 + l4 * 4 + 3 < NNODES) ? 1.f : 0.f };

    int q0 = half ? 6 : 0;
    int qn = half ? 5 : 6;
    for (int qi = 0; qi < qn; ++qi) {
        int qc = q0 + qi;
        bf16x4 qv = *(const bf16x4*)&qb[(qc * 16 + li) * HDIM + l4 * 4];
        bf16x8 qf = __builtin_shufflevector(qv, z4, 0, 1, 2, 3, 4, 5, 6, 7);
        bf16x4 ph[11];
        f32x4 s4 = zf;
        #pragma unroll
        for (int tt = 0; tt < 11; ++tt) {
            bf16x8 a = __builtin_shufflevector(kf[tt], z4, 0, 1, 2, 3, 4, 5, 6, 7);
            f32x4 e = __builtin_amdgcn_mfma_f32_16x16x32_bf16(a, qf, zf, 0, 0, 0);
            f32x4 p;
            p[0] = EXP2F(e[0]); p[1] = EXP2F(e[1]);
            p[2] = EXP2F(e[2]); p[3] = EXP2F(e[3]);
            if (tt == 10) p *= mk;
            s4 += p;
            ph[tt] = __builtin_convertvector(p, bf16x4);
        }
        float sum = (s4[0] + s4[1]) + (s4[2] + s4[3]);
        sum += __shfl_xor(sum, 16);
        sum += __shfl_xor(sum, 32);
        float inv = 1.0f / sum;
        f32x4 o0 = zf, o1 = zf;
        o0 = __builtin_amdgcn_mfma_f32_16x16x32_bf16(vf[0],
                __builtin_shufflevector(ph[0], ph[1], 0,1,2,3,4,5,6,7), o0, 0,0,0);
        o1 = __builtin_amdgcn_mfma_f32_16x16x32_bf16(vf[1],
                __builtin_shufflevector(ph[2], ph[3], 0,1,2,3,4,5,6,7), o1, 0,0,0);
        o0 = __builtin_amdgcn_mfma_f32_16x16x32_bf16(vf[2],
                __builtin_shufflevector(ph[4], ph[5], 0,1,2,3,4,5,6,7), o0, 0,0,0);
        o1 = __builtin_amdgcn_mfma_f32_16x16x32_bf16(vf[3],
                __builtin_shufflevector(ph[6], ph[7], 0,1,2,3,4,5,6,7), o1, 0,0,0);
        o0 = __builtin_amdgcn_mfma_f32_16x16x32_bf16(vf[4],
                __builtin_shufflevector(ph[8], ph[9], 0,1,2,3,4,5,6,7), o0, 0,0,0);
        o1 = __builtin_amdgcn_mfma_f32_16x16x32_bf16(vf[5],
                __builtin_shufflevector(ph[10], z4,    0,1,2,3,4,5,6,7), o1, 0,0,0);
        f32x4 o = o0 + o1;
        int q = qc * 16 + li;
        if (q < NNODES) {
            bf16x4 ov = { (__bf16)(o[0] * inv), (__bf16)(o[1] * inv),
                          (__bf16)(o[2] * inv), (__bf16)(o[3] * inv) };
            *(bf16x4*)&ob[(size_t)q * CDIM + l4 * 4] = ov;
        }
    }
}

// ---------------------------------------------------------------- output projection
__global__ __launch_bounds__(512) void oproj_kernel(const __bf16* __restrict__ ows,
                                                    const float* __restrict__ Wo,
                                                    const float* __restrict__ bo,
                                                    float* __restrict__ out) {
    __shared__ __bf16 Wl[128 * 132];
    int t = threadIdx.x;
    int bt = blockIdx.x;
    #pragma unroll
    for (int i = 0; i < 8; ++i) {
        int idx = i * 512 + t;
        int r = idx >> 5, c = (idx & 31) * 4;
        f32x4 w4 = *(const f32x4*)&Wo[r * 128 + c];
        bf16x4 wb = { (__bf16)w4[0], (__bf16)w4[1], (__bf16)w4[2], (__bf16)w4[3] };
        *(bf16x4*)&Wl[r * 132 + c] = wb;
    }
    __syncthreads();

    int w = t >> 6, lane = t & 63, li = lane & 15, l4 = lane >> 4;
    const bf16x4 z4 = {(__bf16)0.f, (__bf16)0.f, (__bf16)0.f, (__bf16)0.f};
    for (int mt = 0; mt < 2; ++mt) {
        int tbase = mt * 128 + w * 16;
        if (tbase >= NNODES) break;
        int mrow = tbase + li;
        bool mvalid = mrow < NNODES;
        const __bf16* arow = ows + ((size_t)bt * NNODES + mrow) * CDIM;
        f32x4 acc[8] = {};
        #pragma unroll
        for (int kk = 0; kk < 4; ++kk) {
            int kb = kk * 32 + l4 * 4;
            bf16x4 a0 = mvalid ? *(const bf16x4*)(arow + kb)      : z4;
            bf16x4 a1 = mvalid ? *(const bf16x4*)(arow + kb + 16) : z4;
            bf16x8 a = __builtin_shufflevector(a0, a1, 0, 1, 2, 3, 4, 5, 6, 7);
            #pragma unroll
            for (int nt = 0; nt < 8; ++nt) {
                int c = nt * 16 + li;
                bf16x4 b0 = *(const bf16x4*)&Wl[c * 132 + kb];
                bf16x4 b1 = *(const bf16x4*)&Wl[c * 132 + kb + 16];
                bf16x8 b = __builtin_shufflevector(b0, b1, 0, 1, 2, 3, 4, 5, 6, 7);
                acc[nt] = __builtin_amdgcn_mfma_f32_16x16x32_bf16(a, b, acc[nt], 0, 0, 0);
            }
        }
        #pragma unroll
        for (int nt = 0; nt < 8; ++nt) {
            int c = nt * 16 + li;
            float bval = bo[c];
            #pragma unroll
            for (int r = 0; r < 4; ++r) {
                int n = tbase + l4 * 4 + r;
                if (n < NNODES)
                    out[((size_t)bt * NNODES + n) * CDIM + c] = acc[nt][r] + bval;
            }
        }
    }
}

// ---------------------------------------------------------------- launch
extern "C" void kernel_launch(void* const* d_in, const int* in_sizes, int n_in,
                              void* d_out, int out_size, void* d_ws, size_t ws_size,
                              hipStream_t stream) {
    const float* values = (const float*)d_in[0];
    const float* keys   = (const float*)d_in[1];
    const float* query  = (const float*)d_in[2];
    const float* Wv = (const float*)d_in[3];
    const float* bv = (const float*)d_in[4];
    const float* Wk = (const float*)d_in[5];
    const float* bk = (const float*)d_in[6];
    const float* Wq = (const float*)d_in[7];
    const float* bq = (const float*)d_in[8];
    const float* Wo = (const float*)d_in[9];
    const float* bo = (const float*)d_in[10];
    float* out = (float*)d_out;

    __bf16* qws = (__bf16*)d_ws;
    __bf16* kws = qws + QKV_ELEMS;
    __bf16* ows = kws + QKV_ELEMS;          // ws total: 66.8 MB
    __bf16* vt  = (__bf16*)d_out;           // V^T scratch inside d_out (22.5 MB),
                                            // consumed by attn, then oproj overwrites

    hipLaunchKernelGGL(qkv_kernel,  dim3(1536), dim3(512), 0, stream,
                       query, keys, values, Wq, Wk, Wv, bq, bk, bv, qws, kws, vt);
    hipLaunchKernelGGL(attn_kernel, dim3(8192), dim3(64),  0, stream, qws, kws, vt, ows);
    hipLaunchKernelGGL(oproj_kernel, dim3(512), dim3(512), 0, stream, ows, Wo, bo, out);
}

// Round 3
// 102.220 us; speedup vs baseline: 1.3595x; 1.1548x over previous
//
#include <hip/hip_runtime.h>
#include <cstdint>

typedef float   f32x4  __attribute__((ext_vector_type(4)));
typedef __bf16  bf16x4 __attribute__((ext_vector_type(4)));
typedef __bf16  bf16x8 __attribute__((ext_vector_type(8)));

#if __has_builtin(__builtin_amdgcn_exp2f)
#define EXP2F(x) __builtin_amdgcn_exp2f(x)
#else
#define EXP2F(x) exp2f(x)
#endif

#define BT_TOTAL 512
#define NNODES 170
#define CDIM 128
#define HEADS 8
#define HDIM 16
#define SLAB (NNODES*HDIM)           // 2720
#define NPAD 172                     // V^T row stride
#define VSLAB (HDIM*NPAD)            // 2752
#define QKV_ELEMS ((size_t)BT_TOTAL*HEADS*SLAB)
#define S2L2E 0.12753851f            // log2(e)/sqrt(128), folded into Wq/bq

// ---------------------------------------------------------------- fused QKV projection
// iid 0=q -> qws [bt][h][n][d]   (swapped mfma -> 8B vector stores; W,b scaled)
// iid 1=k -> kws [bt][h][n][d]   (swapped)
// iid 2=v -> vt  [bt][h][d][NPAD] (unswapped; vector stores along n)
__global__ __launch_bounds__(512) void qkv_kernel(const float* __restrict__ qin,
    const float* __restrict__ kin, const float* __restrict__ vin,
    const float* __restrict__ Wq, const float* __restrict__ Wk, const float* __restrict__ Wv,
    const float* __restrict__ bq, const float* __restrict__ bk, const float* __restrict__ bv,
    __bf16* __restrict__ qws, __bf16* __restrict__ kws, __bf16* __restrict__ vt) {
    __shared__ __bf16 Wl[128 * 132];
    int t = threadIdx.x;
    int iid = blockIdx.x / BT_TOTAL;
    int bt  = blockIdx.x % BT_TOTAL;
    const float* X    = (iid == 0) ? qin : (iid == 1) ? kin : vin;
    const float* W    = (iid == 0) ? Wq  : (iid == 1) ? Wk  : Wv;
    const float* bias = (iid == 0) ? bq  : (iid == 1) ? bk  : bv;
    float wscale = (iid == 0) ? S2L2E : 1.0f;
    #pragma unroll
    for (int i = 0; i < 8; ++i) {
        int idx = i * 512 + t;
        int r = idx >> 5, c = (idx & 31) * 4;
        f32x4 w4 = *(const f32x4*)&W[r * 128 + c];
        bf16x4 wb = { (__bf16)(w4[0] * wscale), (__bf16)(w4[1] * wscale),
                      (__bf16)(w4[2] * wscale), (__bf16)(w4[3] * wscale) };
        *(bf16x4*)&Wl[r * 132 + c] = wb;
    }
    __syncthreads();

    int w = t >> 6, lane = t & 63, li = lane & 15, l4 = lane >> 4;
    f32x4 zf = {0.f, 0.f, 0.f, 0.f};
    for (int mt = 0; mt < 2; ++mt) {
        int tbase = mt * 128 + w * 16;
        if (tbase >= NNODES) break;              // wave-uniform
        int mrow = tbase + li;
        bool mvalid = mrow < NNODES;
        const float* xrow = X + ((size_t)(bt * NNODES + mrow)) * CDIM;
        f32x4 acc[8] = {};
        #pragma unroll
        for (int kk = 0; kk < 4; ++kk) {
            int kb = kk * 32 + l4 * 4;
            f32x4 a0 = mvalid ? *(const f32x4*)(xrow + kb)      : zf;
            f32x4 a1 = mvalid ? *(const f32x4*)(xrow + kb + 16) : zf;
            bf16x8 a = { (__bf16)a0[0], (__bf16)a0[1], (__bf16)a0[2], (__bf16)a0[3],
                         (__bf16)a1[0], (__bf16)a1[1], (__bf16)a1[2], (__bf16)a1[3] };
            if (iid < 2) {
                #pragma unroll
                for (int nt = 0; nt < 8; ++nt) {
                    int c = nt * 16 + li;
                    bf16x4 b0 = *(const bf16x4*)&Wl[c * 132 + kb];
                    bf16x4 b1 = *(const bf16x4*)&Wl[c * 132 + kb + 16];
                    bf16x8 b = __builtin_shufflevector(b0, b1, 0, 1, 2, 3, 4, 5, 6, 7);
                    // swapped: C^T = W * X^T -> col(li)=n, row(4*l4+r)=channel
                    acc[nt] = __builtin_amdgcn_mfma_f32_16x16x32_bf16(b, a, acc[nt], 0, 0, 0);
                }
            } else {
                #pragma unroll
                for (int nt = 0; nt < 8; ++nt) {
                    int c = nt * 16 + li;
                    bf16x4 b0 = *(const bf16x4*)&Wl[c * 132 + kb];
                    bf16x4 b1 = *(const bf16x4*)&Wl[c * 132 + kb + 16];
                    bf16x8 b = __builtin_shufflevector(b0, b1, 0, 1, 2, 3, 4, 5, 6, 7);
                    // unswapped: col(li)=channel, row(4*l4+r)=n
                    acc[nt] = __builtin_amdgcn_mfma_f32_16x16x32_bf16(a, b, acc[nt], 0, 0, 0);
                }
            }
        }
        if (iid < 2) {
            __bf16* outb = ((iid == 0) ? qws : kws) + ((size_t)bt * HEADS) * SLAB;
            int n = tbase + li;
            if (n < NNODES) {
                #pragma unroll
                for (int nt = 0; nt < 8; ++nt) {
                    // channels c = nt*16 + l4*4 + r  ->  h = nt, d = l4*4 + r
                    f32x4 b4 = *(const f32x4*)&bias[nt * 16 + l4 * 4];
                    f32x4 o = acc[nt] + b4 * wscale;
                    bf16x4 o4 = { (__bf16)o[0], (__bf16)o[1], (__bf16)o[2], (__bf16)o[3] };
                    *(bf16x4*)&outb[(size_t)nt * SLAB + n * HDIM + l4 * 4] = o4;
                }
            }
        } else {
            __bf16* outb = vt + ((size_t)bt * HEADS) * VSLAB;
            int n0 = tbase + l4 * 4;
            #pragma unroll
            for (int nt = 0; nt < 8; ++nt) {
                int c = nt * 16 + li;              // h = nt, d = li
                float bval = bias[c];
                __bf16* dst = outb + (size_t)nt * VSLAB + li * NPAD + n0;
                if (n0 + 3 < NNODES) {
                    bf16x4 o4 = { (__bf16)(acc[nt][0] + bval), (__bf16)(acc[nt][1] + bval),
                                  (__bf16)(acc[nt][2] + bval), (__bf16)(acc[nt][3] + bval) };
                    *(bf16x4*)dst = o4;
                } else {
                    #pragma unroll
                    for (int r = 0; r < 4; ++r)
                        if (n0 + r < NNODES) dst[r] = (__bf16)(acc[nt][r] + bval);
                }
            }
        }
    }
}

// ---------------------------------------------------------------- attention core
// 4 independent wave-units per 256-thread block; unit = (bt, h, q-half).
__global__ __launch_bounds__(256) void attn_kernel(const __bf16* __restrict__ qws,
                                                   const __bf16* __restrict__ kws,
                                                   const __bf16* __restrict__ vt,
                                                   __bf16* __restrict__ ows) {
    int unit = blockIdx.x * 4 + (threadIdx.x >> 6);
    int half = unit & 1, bh = unit >> 1;
    int bt = bh >> 3, h = bh & 7;
    int lane = threadIdx.x & 63, li = lane & 15, l4 = lane >> 4;
    const __bf16* qb  = qws + ((size_t)(bt * HEADS + h)) * SLAB;
    const __bf16* kb  = kws + ((size_t)(bt * HEADS + h)) * SLAB;
    const __bf16* vtb = vt  + ((size_t)(bt * HEADS + h)) * VSLAB;
    __bf16* ob = ows + (size_t)bt * NNODES * CDIM + h * HDIM;
    const __bf16 bz = (__bf16)0.0f;
    const bf16x4 z4 = {bz, bz, bz, bz};
    const f32x4 zf = {0.f, 0.f, 0.f, 0.f};

    bf16x4 kf[11];
    #pragma unroll
    for (int tt = 0; tt < 11; ++tt)
        kf[tt] = *(const bf16x4*)&kb[(tt * 16 + li) * HDIM + l4 * 4];

    bf16x8 vf[6];
    #pragma unroll
    for (int s = 0; s < 5; ++s) {
        bf16x4 a = *(const bf16x4*)&vtb[li * NPAD + 32 * s + 4 * l4];
        bf16x4 b = *(const bf16x4*)&vtb[li * NPAD + 32 * s + 4 * l4 + 16];
        vf[s] = __builtin_shufflevector(a, b, 0, 1, 2, 3, 4, 5, 6, 7);
    }
    {
        bf16x4 a = *(const bf16x4*)&vtb[li * NPAD + 160 + 4 * l4];
        bf16x8 v5 = { (160 + 4 * l4 + 0 < NNODES) ? a[0] : bz,
                      (160 + 4 * l4 + 1 < NNODES) ? a[1] : bz,
                      (160 + 4 * l4 + 2 < NNODES) ? a[2] : bz,
                      (160 + 4 * l4 + 3 < NNODES) ? a[3] : bz,
                      bz, bz, bz, bz };
        vf[5] = v5;
    }
    f32x4 mk = { (160 + l4 * 4 + 0 < NNODES) ? 1.f : 0.f,
                 (160 + l4 * 4 + 1 < NNODES) ? 1.f : 0.f,
                 (160 + l4 * 4 + 2 < NNODES) ? 1.f : 0.f,
                 (160 + l4 * 4 + 3 < NNODES) ? 1.f : 0.f };

    int q0 = half ? 6 : 0;
    int qn = half ? 5 : 6;
    for (int qi = 0; qi < qn; ++qi) {
        int qc = q0 + qi;
        bf16x4 qv = *(const bf16x4*)&qb[(qc * 16 + li) * HDIM + l4 * 4];
        bf16x8 qf = __builtin_shufflevector(qv, z4, 0, 1, 2, 3, 4, 5, 6, 7);
        bf16x4 ph[11];
        f32x4 s4 = zf;
        #pragma unroll
        for (int tt = 0; tt < 11; ++tt) {
            bf16x8 a = __builtin_shufflevector(kf[tt], z4, 0, 1, 2, 3, 4, 5, 6, 7);
            f32x4 e = __builtin_amdgcn_mfma_f32_16x16x32_bf16(a, qf, zf, 0, 0, 0);
            f32x4 p;
            p[0] = EXP2F(e[0]); p[1] = EXP2F(e[1]);
            p[2] = EXP2F(e[2]); p[3] = EXP2F(e[3]);
            if (tt == 10) p *= mk;
            s4 += p;
            ph[tt] = __builtin_convertvector(p, bf16x4);
        }
        float sum = (s4[0] + s4[1]) + (s4[2] + s4[3]);
        sum += __shfl_xor(sum, 16);
        sum += __shfl_xor(sum, 32);
        float inv = 1.0f / sum;
        f32x4 o0 = zf, o1 = zf;
        o0 = __builtin_amdgcn_mfma_f32_16x16x32_bf16(vf[0],
                __builtin_shufflevector(ph[0], ph[1], 0,1,2,3,4,5,6,7), o0, 0,0,0);
        o1 = __builtin_amdgcn_mfma_f32_16x16x32_bf16(vf[1],
                __builtin_shufflevector(ph[2], ph[3], 0,1,2,3,4,5,6,7), o1, 0,0,0);
        o0 = __builtin_amdgcn_mfma_f32_16x16x32_bf16(vf[2],
                __builtin_shufflevector(ph[4], ph[5], 0,1,2,3,4,5,6,7), o0, 0,0,0);
        o1 = __builtin_amdgcn_mfma_f32_16x16x32_bf16(vf[3],
                __builtin_shufflevector(ph[6], ph[7], 0,1,2,3,4,5,6,7), o1, 0,0,0);
        o0 = __builtin_amdgcn_mfma_f32_16x16x32_bf16(vf[4],
                __builtin_shufflevector(ph[8], ph[9], 0,1,2,3,4,5,6,7), o0, 0,0,0);
        o1 = __builtin_amdgcn_mfma_f32_16x16x32_bf16(vf[5],
                __builtin_shufflevector(ph[10], z4,    0,1,2,3,4,5,6,7), o1, 0,0,0);
        f32x4 o = o0 + o1;
        int q = qc * 16 + li;
        if (q < NNODES) {
            bf16x4 ov = { (__bf16)(o[0] * inv), (__bf16)(o[1] * inv),
                          (__bf16)(o[2] * inv), (__bf16)(o[3] * inv) };
            *(bf16x4*)&ob[(size_t)q * CDIM + l4 * 4] = ov;
        }
    }
}

// ---------------------------------------------------------------- output projection
__global__ __launch_bounds__(512) void oproj_kernel(const __bf16* __restrict__ ows,
                                                    const float* __restrict__ Wo,
                                                    const float* __restrict__ bo,
                                                    float* __restrict__ out) {
    __shared__ __bf16 Wl[128 * 132];
    int t = threadIdx.x;
    int bt = blockIdx.x;
    #pragma unroll
    for (int i = 0; i < 8; ++i) {
        int idx = i * 512 + t;
        int r = idx >> 5, c = (idx & 31) * 4;
        f32x4 w4 = *(const f32x4*)&Wo[r * 128 + c];
        bf16x4 wb = { (__bf16)w4[0], (__bf16)w4[1], (__bf16)w4[2], (__bf16)w4[3] };
        *(bf16x4*)&Wl[r * 132 + c] = wb;
    }
    __syncthreads();

    int w = t >> 6, lane = t & 63, li = lane & 15, l4 = lane >> 4;
    const bf16x4 z4 = {(__bf16)0.f, (__bf16)0.f, (__bf16)0.f, (__bf16)0.f};
    for (int mt = 0; mt < 2; ++mt) {
        int tbase = mt * 128 + w * 16;
        if (tbase >= NNODES) break;
        int mrow = tbase + li;
        bool mvalid = mrow < NNODES;
        const __bf16* arow = ows + ((size_t)bt * NNODES + mrow) * CDIM;
        f32x4 acc[8] = {};
        #pragma unroll
        for (int kk = 0; kk < 4; ++kk) {
            int kb = kk * 32 + l4 * 4;
            bf16x4 a0 = mvalid ? *(const bf16x4*)(arow + kb)      : z4;
            bf16x4 a1 = mvalid ? *(const bf16x4*)(arow + kb + 16) : z4;
            bf16x8 a = __builtin_shufflevector(a0, a1, 0, 1, 2, 3, 4, 5, 6, 7);
            #pragma unroll
            for (int nt = 0; nt < 8; ++nt) {
                int c = nt * 16 + li;
                bf16x4 b0 = *(const bf16x4*)&Wl[c * 132 + kb];
                bf16x4 b1 = *(const bf16x4*)&Wl[c * 132 + kb + 16];
                bf16x8 b = __builtin_shufflevector(b0, b1, 0, 1, 2, 3, 4, 5, 6, 7);
                // swapped: col(li)=n, row(4*l4+r)=channel
                acc[nt] = __builtin_amdgcn_mfma_f32_16x16x32_bf16(b, a, acc[nt], 0, 0, 0);
            }
        }
        int n = tbase + li;
        if (n < NNODES) {
            float* orow = out + ((size_t)bt * NNODES + n) * CDIM;
            #pragma unroll
            for (int nt = 0; nt < 8; ++nt) {
                f32x4 b4 = *(const f32x4*)&bo[nt * 16 + l4 * 4];
                f32x4 o = acc[nt] + b4;
                *(f32x4*)&orow[nt * 16 + l4 * 4] = o;
            }
        }
    }
}

// ---------------------------------------------------------------- launch
extern "C" void kernel_launch(void* const* d_in, const int* in_sizes, int n_in,
                              void* d_out, int out_size, void* d_ws, size_t ws_size,
                              hipStream_t stream) {
    const float* values = (const float*)d_in[0];
    const float* keys   = (const float*)d_in[1];
    const float* query  = (const float*)d_in[2];
    const float* Wv = (const float*)d_in[3];
    const float* bv = (const float*)d_in[4];
    const float* Wk = (const float*)d_in[5];
    const float* bk = (const float*)d_in[6];
    const float* Wq = (const float*)d_in[7];
    const float* bq = (const float*)d_in[8];
    const float* Wo = (const float*)d_in[9];
    const float* bo = (const float*)d_in[10];
    float* out = (float*)d_out;

    __bf16* qws = (__bf16*)d_ws;
    __bf16* kws = qws + QKV_ELEMS;
    __bf16* ows = kws + QKV_ELEMS;
    __bf16* vt  = (__bf16*)d_out;   // scratch inside d_out; consumed before oproj writes

    hipLaunchKernelGGL(qkv_kernel,  dim3(1536), dim3(512), 0, stream,
                       query, keys, values, Wq, Wk, Wv, bq, bk, bv, qws, kws, vt);
    hipLaunchKernelGGL(attn_kernel, dim3(2048), dim3(256), 0, stream, qws, kws, vt, ows);
    hipLaunchKernelGGL(oproj_kernel, dim3(512), dim3(512), 0, stream, ows, Wo, bo, out);
}